// Round 4
// baseline (1439.036 us; speedup 1.0000x reference)
//
#include <hip/hip_runtime.h>
#include <cstddef>

typedef _Float16 f16;
typedef f16 f16x4 __attribute__((ext_vector_type(4)));
typedef f16 f16x8 __attribute__((ext_vector_type(8)));
typedef float f32x4 __attribute__((ext_vector_type(4)));

// ---------------------------------------------------------------------------
// MFMA submanifold conv (16x16x32 f16), register-prefetch pipelined.
//   SPLIT: fp16x2 Markidis split (hi + lo*2^12), 3 MFMAs per pair -> ~fp32
//          accuracy (mask-threshold chain). Else single-term f16.
//   INM: 0 = f32 input (split in-kernel, optional att row-scale)
//        1 = f16 single-plane input
//        2 = f16 split-plane input (hi at base, lo at base+in_plane)
//   OUTM: 0 = f32 strided (+ooff), 1 = f16 single, 2 = f16 split planes
// Pipeline per k: [barrier; ds_write regs(k); barrier; issue loads(k+1);
//                  MFMA(k)] -- gather latency hides under MFMA phase.
// LDS row stride C+8 halves: (C/2)%32==16 for C in {32,96,160} -> padded
// stride spreads banks (round-3 counter showed ~5% conflict loss unpadded).
// ---------------------------------------------------------------------------
template<int C, int NTL, bool SPLIT, int INM, int OUTM, int WAVES>
__global__ __launch_bounds__(WAVES * 64)
void mfma_conv(const void* __restrict__ finv, size_t in_plane,
               const float* __restrict__ att,
               const int* __restrict__ nbr,
               const f16* __restrict__ Wb,     // [27][C/32][NTL][TERMS][64][8]
               void* __restrict__ outv, int ostride, int ooff, size_t out_plane,
               int CO_real, int N)
{
    constexpr int KK    = C / 32;
    constexpr int TERMS = SPLIT ? 2 : 1;
    constexpr int LSTR  = C + 8;
    constexpr int ROWS  = WAVES * 16;
    constexpr int PLANE = ROWS * LSTR;
    constexpr int NR    = (INM == 0) ? (C / 16) : (C / 32);
    static_assert(C % 32 == 0, "C multiple of 32");

    __shared__ f16 sA[PLANE * (SPLIT ? 2 : 1)];

    const int tid  = threadIdx.x;
    const int lane = tid & 63;
    const int w    = tid >> 6;
    const int n0   = blockIdx.x * ROWS;
    const int grow = tid >> 2;          // 4 threads per staged row
    const int gcol = tid & 3;
    const int nrow = n0 + grow;
    const bool rvalid = nrow < N;

    float4 vf[(INM == 0) ? NR : 1];
    f16x8  vh[(INM != 0) ? NR : 1];
    f16x8  vl[(INM == 2) ? NR : 1];
    float  aval = 1.f;

    auto gather = [&](int idx) {
        if constexpr (INM == 0) {
            const float* fin = (const float*)finv;
#pragma unroll
            for (int i = 0; i < NR; ++i) {
                float4 zz = make_float4(0.f, 0.f, 0.f, 0.f);
                vf[i] = (idx >= 0)
                    ? *(const float4*)(fin + (size_t)idx * C + (gcol + i * 4) * 4) : zz;
            }
            if (att != nullptr) aval = (idx >= 0) ? att[idx] : 1.f;
        } else if constexpr (INM == 1) {
            const f16* fin = (const f16*)finv;
#pragma unroll
            for (int i = 0; i < NR; ++i) {
                f16x8 zz = {};
                vh[i] = (idx >= 0)
                    ? *(const f16x8*)(fin + (size_t)idx * C + (gcol + i * 4) * 8) : zz;
            }
        } else {
            const f16* fin = (const f16*)finv;
#pragma unroll
            for (int i = 0; i < NR; ++i) {
                f16x8 zz = {};
                const size_t off = (size_t)idx * C + (gcol + i * 4) * 8;
                vh[i] = (idx >= 0) ? *(const f16x8*)(fin + off) : zz;
                vl[i] = (idx >= 0) ? *(const f16x8*)(fin + in_plane + off) : zz;
            }
        }
    };

    auto write_lds = [&]() {
        if constexpr (INM == 0) {
#pragma unroll
            for (int i = 0; i < NR; ++i) {
                const int c4 = gcol + i * 4;
                const float xs[4] = {vf[i].x * aval, vf[i].y * aval,
                                     vf[i].z * aval, vf[i].w * aval};
                f16x4 hi, lo;
#pragma unroll
                for (int j = 0; j < 4; ++j) {
                    const f16 h = (f16)xs[j];
                    hi[j] = h;
                    lo[j] = (f16)((xs[j] - (float)h) * 4096.f);
                }
                *(f16x4*)&sA[grow * LSTR + c4 * 4] = hi;
                if constexpr (SPLIT)
                    *(f16x4*)&sA[PLANE + grow * LSTR + c4 * 4] = lo;
            }
        } else if constexpr (INM == 1) {
#pragma unroll
            for (int i = 0; i < NR; ++i)
                *(f16x8*)&sA[grow * LSTR + (gcol + i * 4) * 8] = vh[i];
        } else {
#pragma unroll
            for (int i = 0; i < NR; ++i) {
                *(f16x8*)&sA[grow * LSTR + (gcol + i * 4) * 8] = vh[i];
                *(f16x8*)&sA[PLANE + grow * LSTR + (gcol + i * 4) * 8] = vl[i];
            }
        }
    };

    f32x4 acc[NTL], acc2[NTL];
#pragma unroll
    for (int nt = 0; nt < NTL; ++nt) {
        acc[nt]  = (f32x4){0.f, 0.f, 0.f, 0.f};
        acc2[nt] = (f32x4){0.f, 0.f, 0.f, 0.f};
    }

    // prologue: data for k=0, index for k=1
    int idxB = rvalid ? nbr[(size_t)nrow * 27] : -1;
    gather(idxB);
    idxB = rvalid ? nbr[(size_t)nrow * 27 + 1] : -1;

    for (int k = 0; k < 27; ++k) {
        __syncthreads();                 // all waves done reading LDS(k-1)
        write_lds();                     // regs -> LDS (waitcnt lands here)
        __syncthreads();                 // LDS(k) ready
        if (k + 1 < 27) gather(idxB);    // issue loads for k+1 (used next iter)
        if (k + 2 < 27) idxB = rvalid ? nbr[(size_t)nrow * 27 + k + 2] : -1;

        const int arow = w * 16 + (lane & 15);
#pragma unroll
        for (int kk = 0; kk < KK; ++kk) {
            const f16x8 ah = *(const f16x8*)&sA[arow * LSTR + kk * 32 + (lane >> 4) * 8];
            f16x8 al = {};
            if constexpr (SPLIT)
                al = *(const f16x8*)&sA[PLANE + arow * LSTR + kk * 32 + (lane >> 4) * 8];
            const f16* wk = Wb + ((size_t)(k * KK + kk) * NTL * TERMS) * 512 + lane * 8;
#pragma unroll
            for (int nt = 0; nt < NTL; ++nt) {
                const f16x8 bh = *(const f16x8*)(wk + (size_t)nt * TERMS * 512);
                acc[nt] = __builtin_amdgcn_mfma_f32_16x16x32_f16(ah, bh, acc[nt], 0, 0, 0);
                if constexpr (SPLIT) {
                    const f16x8 bl = *(const f16x8*)(wk + (size_t)nt * TERMS * 512 + 512);
                    acc2[nt] = __builtin_amdgcn_mfma_f32_16x16x32_f16(ah, bl, acc2[nt], 0, 0, 0);
                    acc2[nt] = __builtin_amdgcn_mfma_f32_16x16x32_f16(al, bh, acc2[nt], 0, 0, 0);
                }
            }
        }
    }

    // epilogue: D col=lane&15, row=(lane>>4)*4+j
    const int col = lane & 15;
    const int rg  = lane >> 4;
#pragma unroll
    for (int nt = 0; nt < NTL; ++nt) {
#pragma unroll
        for (int j = 0; j < 4; ++j) {
            float r = acc[nt][j];
            if constexpr (SPLIT) r += acc2[nt][j] * (1.f / 4096.f);
            const int n  = n0 + w * 16 + rg * 4 + j;
            const int co = nt * 16 + col;
            if (n < N && co < CO_real) {
                if constexpr (OUTM == 0) {
                    ((float*)outv)[(size_t)n * ostride + ooff + co] = r;
                } else if constexpr (OUTM == 1) {
                    ((f16*)outv)[(size_t)n * ostride + co] = (f16)r;
                } else {
                    f16* o = (f16*)outv;
                    const f16 h = (f16)r;
                    o[(size_t)n * ostride + co] = h;
                    o[out_plane + (size_t)n * ostride + co] = (f16)((r - (float)h) * 4096.f);
                }
            }
        }
    }
}

// nbrm[i] = nbr[i] if that neighbor survives the attention mask, else -1.
__global__ __launch_bounds__(256)
void remap_nbr(const int* __restrict__ nbr, const float* __restrict__ att,
               int* __restrict__ nbrm, size_t total)
{
    const size_t i = (size_t)blockIdx.x * blockDim.x + threadIdx.x;
    if (i >= total) return;
    const int j = nbr[i];
    nbrm[i] = (j >= 0 && att[j] > 0.5f) ? j : -1;
}

// Pack fp32 W[27][C][CO_real] into f16 fragment order (hi term, then scaled lo).
__global__ __launch_bounds__(256)
void pack_w_f16(const float* __restrict__ W, f16* __restrict__ Wb,
                int C, int CO_real, int NTL, int TERMS)
{
    const int KK = C / 32;
    const int F  = 27 * KK * NTL * TERMS;
    const int t  = blockIdx.x * blockDim.x + threadIdx.x;
    if (t >= F * 64) return;
    const int lane = t & 63;
    const int f    = t >> 6;
    const int term = f % TERMS;
    const int nt   = (f / TERMS) % NTL;
    const int kk   = (f / (TERMS * NTL)) % KK;
    const int k    = f / (TERMS * NTL * KK);
    const int co   = nt * 16 + (lane & 15);
#pragma unroll
    for (int j = 0; j < 8; ++j) {
        const int ci = kk * 32 + (lane >> 4) * 8 + j;
        const float x = (co < CO_real) ? W[((size_t)k * C + ci) * CO_real + co] : 0.f;
        const f16 h = (f16)x;
        Wb[(size_t)t * 8 + j] = (term == 0) ? h : (f16)((x - (float)h) * 4096.f);
    }
}

// Pack [27,32,{3,2,5}] heads into fp32 [27,32,10].
__global__ __launch_bounds__(256)
void pack_head_w(const float* __restrict__ wp, const float* __restrict__ ws,
                 const float* __restrict__ wt, float* __restrict__ Wh)
{
    const int i = blockIdx.x * blockDim.x + threadIdx.x;
    if (i >= 27 * 32 * 10) return;
    const int co = i % 10;
    const int ci = (i / 10) % 32;
    const int k  = i / 320;
    float v;
    if (co < 3)      v = wp[(k * 32 + ci) * 3 + co];
    else if (co < 5) v = ws[(k * 32 + ci) * 2 + (co - 3)];
    else             v = wt[(k * 32 + ci) * 5 + (co - 5)];
    Wh[i] = v;
}

__global__ __launch_bounds__(256)
void coords_kernel(const int* __restrict__ coords, float* __restrict__ ppn, int N)
{
    const int i = blockIdx.x * blockDim.x + threadIdx.x;
    if (i < N * 4) ppn[(size_t)(i >> 2) * 6 + (i & 3)] = (float)coords[i];
}

__global__ __launch_bounds__(256)
void att_kernel(const float* __restrict__ ppn, const int* __restrict__ parent,
                float* __restrict__ att, int N)
{
    const int i = blockIdx.x * blockDim.x + threadIdx.x;
    if (i >= N) return;
    const int p = parent[i];
    const float s0 = ppn[(size_t)p * 6 + 4];
    const float s1 = ppn[(size_t)p * 6 + 5];
    const float m  = fmaxf(s0, s1);
    const float e0 = expf(s0 - m);
    const float e1 = expf(s1 - m);
    const float p1 = e1 / (e0 + e1);
    att[i] = (p1 > 0.8f) ? 1.f : 0.f;
}

extern "C" void kernel_launch(void* const* d_in, const int* in_sizes, int n_in,
                              void* d_out, int out_size, void* d_ws, size_t ws_size,
                              hipStream_t stream)
{
    const float* f1       = (const float*)d_in[0];
    const float* f2       = (const float*)d_in[1];
    const float* f3       = (const float*)d_in[2];
    const float* w1_conv  = (const float*)d_in[3];
    const float* w1_score = (const float*)d_in[4];
    const float* w2_conv  = (const float*)d_in[5];
    const float* w2_score = (const float*)d_in[6];
    const float* w3_conv  = (const float*)d_in[7];
    const float* w3_pix   = (const float*)d_in[8];
    const float* w3_score = (const float*)d_in[9];
    const float* w3_type  = (const float*)d_in[10];
    const int* coords1    = (const int*)d_in[11];
    const int* coords2    = (const int*)d_in[12];
    const int* nbr1       = (const int*)d_in[13];
    const int* nbr2       = (const int*)d_in[14];
    const int* nbr3       = (const int*)d_in[15];
    const int* parent12   = (const int*)d_in[16];
    const int* parent23   = (const int*)d_in[17];

    const int N1 = in_sizes[0] / 160;   // 20000
    const int N2 = in_sizes[1] / 96;    // 160000
    const int N3 = in_sizes[2] / 32;    // 320000

    // Output layout: points[N3,10] | ppn1[N1,6] | ppn2[N2,6] | att[N2] | att2[N3]
    float* points = (float*)d_out;
    float* ppn1   = points + (size_t)N3 * 10;
    float* ppn2   = ppn1 + (size_t)N1 * 6;
    float* attn   = ppn2 + (size_t)N2 * 6;
    float* attn2  = attn + (size_t)N2;

    // Workspace (region reuse by lifetime):
    //  X: xsplit (N1*160*2 f16, conv1->score1)  then  nbr2m (N2*27 int)
    //  Y: ysplit (N2*96*2 f16, conv2->score2)   then  z (N3*32 f16)
    //  W: packed weights
    char* wsb = (char*)d_ws;
    f16* xs    = (f16*)wsb;
    int* nbr2m = (int*)wsb;
    const size_t szX = (((size_t)N2 * 27 * 4) + 255) & ~(size_t)255;  // 17.3 MB
    f16* ys = (f16*)(wsb + szX);
    f16* z  = ys;
    const size_t szY = (size_t)N2 * 96 * 2 * sizeof(f16);             // 61.4 MB
    float* Whf = (float*)(wsb + szX + szY);
    f16* Wb1 = (f16*)(Whf + 27 * 32 * 10);
    f16* Ws1 = Wb1 + (size_t)27 * 5 * 10 * 2 * 512;
    f16* Wb2 = Ws1 + (size_t)27 * 5 * 1 * 2 * 512;
    f16* Ws2 = Wb2 + (size_t)27 * 3 * 6 * 2 * 512;
    f16* Wb3 = Ws2 + (size_t)27 * 3 * 1 * 2 * 512;
    f16* Wbh = Wb3 + (size_t)27 * 1 * 2 * 1 * 512;

    // ---- weight packing ----
    pack_head_w<<<(27 * 32 * 10 + 255) / 256, 256, 0, stream>>>(w3_pix, w3_score, w3_type, Whf);
    pack_w_f16<<<(27 * 5 * 10 * 2 * 64 + 255) / 256, 256, 0, stream>>>(w1_conv, Wb1, 160, 160, 10, 2);
    pack_w_f16<<<(27 * 5 * 1 * 2 * 64 + 255) / 256, 256, 0, stream>>>(w1_score, Ws1, 160, 2, 1, 2);
    pack_w_f16<<<(27 * 3 * 6 * 2 * 64 + 255) / 256, 256, 0, stream>>>(w2_conv, Wb2, 96, 96, 6, 2);
    pack_w_f16<<<(27 * 3 * 1 * 2 * 64 + 255) / 256, 256, 0, stream>>>(w2_score, Ws2, 96, 2, 1, 2);
    pack_w_f16<<<(27 * 1 * 2 * 1 * 64 + 255) / 256, 256, 0, stream>>>(w3_conv, Wb3, 32, 32, 2, 1);
    pack_w_f16<<<(27 * 1 * 1 * 1 * 64 + 255) / 256, 256, 0, stream>>>(Whf, Wbh, 32, 10, 1, 1);

    coords_kernel<<<(N1 * 4 + 255) / 256, 256, 0, stream>>>(coords1, ppn1, N1);
    coords_kernel<<<(N2 * 4 + 255) / 256, 256, 0, stream>>>(coords2, ppn2, N2);

    // ---- level 1 ----
    mfma_conv<160, 10, true, 0, 2, 4><<<(N1 + 63) / 64, 256, 0, stream>>>(
        f1, 0, nullptr, nbr1, Wb1, xs, 160, 0, (size_t)N1 * 160, 160, N1);
    mfma_conv<160, 1, true, 2, 0, 4><<<(N1 + 63) / 64, 256, 0, stream>>>(
        xs, (size_t)N1 * 160, nullptr, nbr1, Ws1, ppn1, 6, 4, 0, 2, N1);
    att_kernel<<<(N2 + 255) / 256, 256, 0, stream>>>(ppn1, parent12, attn, N2);

    // ---- level 2 ----
    remap_nbr<<<(int)(((size_t)N2 * 27 + 255) / 256), 256, 0, stream>>>(
        nbr2, attn, nbr2m, (size_t)N2 * 27);
    mfma_conv<96, 6, true, 0, 2, 8><<<(N2 + 127) / 128, 512, 0, stream>>>(
        f2, 0, nullptr, nbr2m, Wb2, ys, 96, 0, (size_t)N2 * 96, 96, N2);
    mfma_conv<96, 1, true, 2, 0, 4><<<(N2 + 63) / 64, 256, 0, stream>>>(
        ys, (size_t)N2 * 96, nullptr, nbr2, Ws2, ppn2, 6, 4, 0, 2, N2);
    att_kernel<<<(N3 + 255) / 256, 256, 0, stream>>>(ppn2, parent23, attn2, N3);

    // ---- level 3 (points chain, single-term f16) ----
    mfma_conv<32, 2, false, 0, 1, 4><<<(N3 + 63) / 64, 256, 0, stream>>>(
        f3, 0, attn2, nbr3, Wb3, z, 32, 0, 0, 32, N3);
    mfma_conv<32, 1, false, 1, 0, 4><<<(N3 + 63) / 64, 256, 0, stream>>>(
        z, 0, nullptr, nbr3, Wbh, points, 10, 0, 0, 10, N3);
}

// Round 5
// 718.386 us; speedup vs baseline: 2.0032x; 2.0032x over previous
//
#include <hip/hip_runtime.h>
#include <cstddef>

typedef _Float16 f16;
typedef f16 f16x4 __attribute__((ext_vector_type(4)));
typedef f16 f16x8 __attribute__((ext_vector_type(8)));
typedef float f32x4 __attribute__((ext_vector_type(4)));

// async global->LDS, 16B per lane. LDS dest = uniform base + lane*16 (HW);
// global src is per-lane.
__device__ inline void gld_lds16(const f16* g, f16* l) {
    __builtin_amdgcn_global_load_lds(
        (const __attribute__((address_space(1))) void*)g,
        (__attribute__((address_space(3))) void*)l, 16, 0, 0);
}

// ---------------------------------------------------------------------------
// MFMA submanifold conv, A-direct / B-in-LDS.
//  - wave owns 16 sites; A fragment = per-lane 16B global load from pre-split
//    f16 planes (hi at base, lo at base+in_plane). Row N of input = zeros;
//    missing neighbors (idx<0) and tail sites map there -> branch-free.
//  - B (packed fragments) staged per-k into LDS double-buffer via
//    global_load_lds; ONE barrier per k; stage issued at phase start so the
//    pre-barrier drain hides under the MFMA phase.
//  - TERMS=2: Markidis f16 split (hi + lo*2^12), 3 MFMAs per fragment pair
//    (~fp32 accuracy for the mask-threshold chain). TERMS=1: plain f16.
//  - BMODE 0: whole weight set staged once (27*CH KB), no k-loop barriers.
//  - CS col-split: block cs handles co tiles [cs*NTB, (cs+1)*NTB).
//    grid.x = tilesPad*CS with tilesPad % 8 == 0 so cs-twins share an XCD.
// ---------------------------------------------------------------------------
template<int C, int NTB, int CS, int TERMS, int WAVES, int BMODE, int OUTM>
__global__ __launch_bounds__(WAVES * 64)
void conv_mfma(const f16* __restrict__ fin, size_t in_plane,
               const int* __restrict__ nbr,
               const f16* __restrict__ Wb,
               void* __restrict__ outv, int ostride, int ooff, size_t out_plane,
               int CO_real, int N, int Nstore, int tilesPad)
{
    constexpr int KK   = C / 32;
    constexpr int CH   = KK * NTB * TERMS;      // 1KB fragments per (k, cs)
    constexpr int ROWS = WAVES * 16;
    constexpr int BUFS = (BMODE == 0) ? 27 : 2;
    __shared__ f16 sB[BUFS * CH * 512];

    const int tid  = threadIdx.x;
    const int lane = tid & 63;
    const int w    = tid >> 6;
    const int tile = blockIdx.x % tilesPad;
    const int cs   = blockIdx.x / tilesPad;
    const int n0   = tile * ROWS;
    const int site = n0 + w * 16 + (lane & 15);
    const bool sv  = site < N;
    const int NZ   = N;                          // zero row
    const int h8   = (lane >> 4) * 8;

    auto stageK = [&](int k, int buf) {
        const f16* src = Wb + ((size_t)(k * CS + cs) * CH) * 512 + lane * 8;
        f16* dst = &sB[(size_t)buf * CH * 512];
        for (int c = w; c < CH; c += WAVES)
            gld_lds16(src + (size_t)c * 512, dst + (size_t)c * 512);
    };

    f32x4 acc[NTB];
    f32x4 acc2[NTB];
#pragma unroll
    for (int nt = 0; nt < NTB; ++nt) {
        acc[nt]  = (f32x4){0.f, 0.f, 0.f, 0.f};
        acc2[nt] = (f32x4){0.f, 0.f, 0.f, 0.f};
    }

    if constexpr (BMODE == 0) {
        for (int c = w; c < 27 * CH; c += WAVES)
            gld_lds16(Wb + (size_t)c * 512 + lane * 8, &sB[(size_t)c * 512]);
    } else {
        stageK(0, 0);
    }

    int idxC;
    { int r = sv ? nbr[(size_t)site * 27] : -1; idxC = (r < 0) ? NZ : r; }
    __syncthreads();   // B(0) (or all B) staged

    int cur = 0;
    for (int k = 0; k < 27; ++k) {
        if (BMODE == 1 && k + 1 < 27) stageK(k + 1, cur ^ 1);

        // A fragments for this k (per-lane direct gather)
        const f16* arow = fin + (size_t)idxC * C + h8;
        f16x8 va[KK], vl[KK];
#pragma unroll
        for (int kk = 0; kk < KK; ++kk) {
            va[kk] = *(const f16x8*)(arow + kk * 32);
            if constexpr (TERMS == 2)
                vl[kk] = *(const f16x8*)(arow + in_plane + kk * 32);
        }
        // prefetch next k's neighbor index
        int idxN = NZ;
        if (k + 1 < 27) {
            int r = sv ? nbr[(size_t)site * 27 + k + 1] : -1;
            idxN = (r < 0) ? NZ : r;
        }

        const f16* sBc = &sB[(size_t)((BMODE == 0) ? k : cur) * CH * 512] + lane * 8;
#pragma unroll
        for (int kk = 0; kk < KK; ++kk) {
#pragma unroll
            for (int nt = 0; nt < NTB; ++nt) {
                const f16* bp = sBc + (size_t)((kk * NTB + nt) * TERMS) * 512;
                const f16x8 bh = *(const f16x8*)bp;
                acc[nt] = __builtin_amdgcn_mfma_f32_16x16x32_f16(va[kk], bh, acc[nt], 0, 0, 0);
                if constexpr (TERMS == 2) {
                    const f16x8 bl = *(const f16x8*)(bp + 512);
                    acc2[nt] = __builtin_amdgcn_mfma_f32_16x16x32_f16(va[kk], bl, acc2[nt], 0, 0, 0);
                    acc2[nt] = __builtin_amdgcn_mfma_f32_16x16x32_f16(vl[kk], bh, acc2[nt], 0, 0, 0);
                }
            }
        }
        idxC = idxN;
        if constexpr (BMODE == 1) { __syncthreads(); cur ^= 1; }
    }

    // epilogue: D col=lane&15, row=(lane>>4)*4+j
    const int colg = lane & 15;
    const int rg   = lane >> 4;
#pragma unroll
    for (int nt = 0; nt < NTB; ++nt) {
#pragma unroll
        for (int j = 0; j < 4; ++j) {
            float r = acc[nt][j];
            if constexpr (TERMS == 2) r += acc2[nt][j] * (1.f / 4096.f);
            const int n  = n0 + w * 16 + rg * 4 + j;
            const int co = (cs * NTB + nt) * 16 + colg;
            if (n < Nstore && co < CO_real) {
                if constexpr (OUTM == 0) {
                    ((float*)outv)[(size_t)n * ostride + ooff + co] = r;
                } else if constexpr (OUTM == 1) {
                    ((f16*)outv)[(size_t)n * ostride + co] = (f16)r;
                } else {
                    f16* o = (f16*)outv;
                    const f16 h = (f16)r;
                    o[(size_t)n * ostride + co] = h;
                    o[out_plane + (size_t)n * ostride + co] = (f16)((r - (float)h) * 4096.f);
                }
            }
        }
    }
}

// ---------------------------------------------------------------------------
// Pre-pass: f32 rows (optionally x att-mask) -> f16 split planes, plus a
// zero row at index N (gather target for missing neighbors / tail sites).
// ---------------------------------------------------------------------------
template<int TERMS>
__global__ __launch_bounds__(256)
void prepass(const float* __restrict__ f, const float* __restrict__ att,
             f16* __restrict__ dst, size_t plane, int C4, int N)
{
    const size_t i = (size_t)blockIdx.x * 256 + threadIdx.x;
    const size_t total = (size_t)(N + 1) * C4;
    if (i >= total) return;
    const int row = (int)(i / C4);
    float4 v = make_float4(0.f, 0.f, 0.f, 0.f);
    if (row < N) {
        v = *(const float4*)(f + i * 4);
        if (att != nullptr) {
            const float a = att[row];
            v.x *= a; v.y *= a; v.z *= a; v.w *= a;
        }
    }
    const float xs[4] = {v.x, v.y, v.z, v.w};
    f16x4 hi, lo;
#pragma unroll
    for (int j = 0; j < 4; ++j) {
        const f16 h = (f16)xs[j];
        hi[j] = h;
        lo[j] = (f16)((xs[j] - (float)h) * 4096.f);
    }
    *(f16x4*)(dst + i * 4) = hi;
    if constexpr (TERMS == 2)
        *(f16x4*)(dst + plane + i * 4) = lo;
}

// Pack fp32 W[27][C][CO_real] into fragment chunks:
// chunk id = ((((k*CS + cs)*KK + kk)*NTB + nt)*TERMS + term), 512 f16 each.
__global__ __launch_bounds__(256)
void pack_w_f16(const float* __restrict__ W, f16* __restrict__ Wb,
                int C, int CO_real, int CS, int NTB, int TERMS)
{
    const int KK = C / 32;
    const int total = 27 * CS * KK * NTB * TERMS * 64;
    const int t = blockIdx.x * blockDim.x + threadIdx.x;
    if (t >= total) return;
    const int lane = t & 63;
    int cid = t >> 6;
    const int term = cid % TERMS; cid /= TERMS;
    const int nt   = cid % NTB;   cid /= NTB;
    const int kk   = cid % KK;    cid /= KK;
    const int cs   = cid % CS;
    const int k    = cid / CS;
    const int co   = (cs * NTB + nt) * 16 + (lane & 15);
#pragma unroll
    for (int j = 0; j < 8; ++j) {
        const int ci = kk * 32 + (lane >> 4) * 8 + j;
        const float x = (co < CO_real) ? W[((size_t)k * C + ci) * CO_real + co] : 0.f;
        const f16 h = (f16)x;
        Wb[(size_t)t * 8 + j] = (term == 0) ? h : (f16)((x - (float)h) * 4096.f);
    }
}

// Pack [27,32,{3,2,5}] heads into fp32 [27,32,10].
__global__ __launch_bounds__(256)
void pack_head_w(const float* __restrict__ wp, const float* __restrict__ ws,
                 const float* __restrict__ wt, float* __restrict__ Wh)
{
    const int i = blockIdx.x * blockDim.x + threadIdx.x;
    if (i >= 27 * 32 * 10) return;
    const int co = i % 10;
    const int ci = (i / 10) % 32;
    const int k  = i / 320;
    float v;
    if (co < 3)      v = wp[(k * 32 + ci) * 3 + co];
    else if (co < 5) v = ws[(k * 32 + ci) * 2 + (co - 3)];
    else             v = wt[(k * 32 + ci) * 5 + (co - 5)];
    Wh[i] = v;
}

__global__ __launch_bounds__(256)
void coords_kernel(const int* __restrict__ coords, float* __restrict__ ppn, int N)
{
    const int i = blockIdx.x * blockDim.x + threadIdx.x;
    if (i < N * 4) ppn[(size_t)(i >> 2) * 6 + (i & 3)] = (float)coords[i];
}

__global__ __launch_bounds__(256)
void att_kernel(const float* __restrict__ ppn, const int* __restrict__ parent,
                float* __restrict__ att, int N)
{
    const int i = blockIdx.x * blockDim.x + threadIdx.x;
    if (i >= N) return;
    const int p = parent[i];
    const float s0 = ppn[(size_t)p * 6 + 4];
    const float s1 = ppn[(size_t)p * 6 + 5];
    const float m  = fmaxf(s0, s1);
    const float e0 = expf(s0 - m);
    const float e1 = expf(s1 - m);
    const float p1 = e1 / (e0 + e1);
    att[i] = (p1 > 0.8f) ? 1.f : 0.f;
}

extern "C" void kernel_launch(void* const* d_in, const int* in_sizes, int n_in,
                              void* d_out, int out_size, void* d_ws, size_t ws_size,
                              hipStream_t stream)
{
    const float* f1       = (const float*)d_in[0];
    const float* f2       = (const float*)d_in[1];
    const float* f3       = (const float*)d_in[2];
    const float* w1_conv  = (const float*)d_in[3];
    const float* w1_score = (const float*)d_in[4];
    const float* w2_conv  = (const float*)d_in[5];
    const float* w2_score = (const float*)d_in[6];
    const float* w3_conv  = (const float*)d_in[7];
    const float* w3_pix   = (const float*)d_in[8];
    const float* w3_score = (const float*)d_in[9];
    const float* w3_type  = (const float*)d_in[10];
    const int* coords1    = (const int*)d_in[11];
    const int* coords2    = (const int*)d_in[12];
    const int* nbr1       = (const int*)d_in[13];
    const int* nbr2       = (const int*)d_in[14];
    const int* nbr3       = (const int*)d_in[15];
    const int* parent12   = (const int*)d_in[16];
    const int* parent23   = (const int*)d_in[17];

    const int N1 = in_sizes[0] / 160;   // 20000
    const int N2 = in_sizes[1] / 96;    // 160000
    const int N3 = in_sizes[2] / 32;    // 320000

    // Output layout: points[N3,10] | ppn1[N1,6] | ppn2[N2,6] | att[N2] | att2[N3]
    float* points = (float*)d_out;
    float* ppn1   = points + (size_t)N3 * 10;
    float* ppn2   = ppn1 + (size_t)N1 * 6;
    float* attn   = ppn2 + (size_t)N2 * 6;
    float* attn2  = attn + (size_t)N2;

    // Workspace (all conv inputs have N+1 rows; row N = zeros).
    const size_t p1 = (size_t)(N1 + 1) * 160;
    const size_t p2 = (size_t)(N2 + 1) * 96;
    const size_t p3 = (size_t)(N3 + 1) * 32;
    f16* f1s = (f16*)d_ws;            // 2*p1   (dead after conv1)
    f16* xs  = f1s + 2 * p1;          // 2*p1   (dead after score1)
    f16* f3s = f1s;                   // p3 <= 4*p1, reuses R1+R2
    f16* f2s = xs + 2 * p1;           // 2*p2   (dead after conv2)
    f16* ys  = f2s + 2 * p2;          // 2*p2
    f16* zs  = f2s;                   // p3 <= 2*p2, reuses f2s
    float* Whf = (float*)(ys + 2 * p2);
    f16* Wb1 = (f16*)(Whf + 27 * 32 * 10);   // 27*5cs*5kk*2nt*2t = 2700 chunks
    f16* Ws1 = Wb1 + (size_t)2700 * 512;     // 27*5*1*2 = 270
    f16* Wb2 = Ws1 + (size_t)270 * 512;      // 27*2cs*3kk*3nt*2t = 972
    f16* Ws2 = Wb2 + (size_t)972 * 512;      // 27*3*1*2 = 162
    f16* Wb3 = Ws2 + (size_t)162 * 512;      // 27*1*2*1 = 54
    f16* Wbh = Wb3 + (size_t)54 * 512;       // 27

    // ---- weight packing ----
    pack_head_w<<<(27 * 32 * 10 + 255) / 256, 256, 0, stream>>>(w3_pix, w3_score, w3_type, Whf);
    pack_w_f16<<<(2700 * 64 + 255) / 256, 256, 0, stream>>>(w1_conv, Wb1, 160, 160, 5, 2, 2);
    pack_w_f16<<<(270 * 64 + 255) / 256, 256, 0, stream>>>(w1_score, Ws1, 160, 2, 1, 1, 2);
    pack_w_f16<<<(972 * 64 + 255) / 256, 256, 0, stream>>>(w2_conv, Wb2, 96, 96, 2, 3, 2);
    pack_w_f16<<<(162 * 64 + 255) / 256, 256, 0, stream>>>(w2_score, Ws2, 96, 2, 1, 1, 2);
    pack_w_f16<<<(54 * 64 + 255) / 256, 256, 0, stream>>>(w3_conv, Wb3, 32, 32, 1, 2, 1);
    pack_w_f16<<<(27 * 64 + 255) / 256, 256, 0, stream>>>(Whf, Wbh, 32, 10, 1, 1, 1);

    coords_kernel<<<(N1 * 4 + 255) / 256, 256, 0, stream>>>(coords1, ppn1, N1);
    coords_kernel<<<(N2 * 4 + 255) / 256, 256, 0, stream>>>(coords2, ppn2, N2);

    // ---- level 1 ----
    prepass<2><<<(int)(((size_t)(N1 + 1) * 40 + 255) / 256), 256, 0, stream>>>(
        f1, nullptr, f1s, p1, 40, N1);
    // conv1: C=160 NTB=2 CS=5 split, 8 waves, dbuf. tiles=157 -> pad 160.
    conv_mfma<160, 2, 5, 2, 8, 1, 2><<<160 * 5, 512, 0, stream>>>(
        f1s, p1, nbr1, Wb1, xs, 160, 0, p1, 160, N1, N1 + 1, 160);
    // score1: C=160 NTB=1 split, 4 waves. tiles=313.
    conv_mfma<160, 1, 1, 2, 4, 1, 0><<<313, 256, 0, stream>>>(
        xs, p1, nbr1, Ws1, ppn1, 6, 4, 0, 2, N1, N1, 313);
    att_kernel<<<(N2 + 255) / 256, 256, 0, stream>>>(ppn1, parent12, attn, N2);

    // ---- level 2 ----
    prepass<2><<<(int)(((size_t)(N2 + 1) * 24 + 255) / 256), 256, 0, stream>>>(
        f2, attn, f2s, p2, 24, N2);
    // conv2: C=96 NTB=3 CS=2 split, 8 waves, dbuf. tiles=1251 -> pad 1256.
    conv_mfma<96, 3, 2, 2, 8, 1, 2><<<1256 * 2, 512, 0, stream>>>(
        f2s, p2, nbr2, Wb2, ys, 96, 0, p2, 96, N2, N2 + 1, 1256);
    // score2: C=96 NTB=1 split, 4 waves. tiles=2500.
    conv_mfma<96, 1, 1, 2, 4, 1, 0><<<2500, 256, 0, stream>>>(
        ys, p2, nbr2, Ws2, ppn2, 6, 4, 0, 2, N2, N2, 2500);
    att_kernel<<<(N3 + 255) / 256, 256, 0, stream>>>(ppn2, parent23, attn2, N3);

    // ---- level 3 (points chain, single-term f16) ----
    prepass<1><<<(int)(((size_t)(N3 + 1) * 8 + 255) / 256), 256, 0, stream>>>(
        f3, attn2, f3s, 0, 8, N3);
    // conv3: C=32 NTB=2 whole-B (54KB), no k-loop barriers. tiles=2501.
    conv_mfma<32, 2, 1, 1, 8, 0, 1><<<2501, 512, 0, stream>>>(
        f3s, 0, nbr3, Wb3, zs, 32, 0, 0, 32, N3, N3 + 1, 2501);
    // head: C=32 NTB=1 whole-B (27KB). tiles=2500.
    conv_mfma<32, 1, 1, 1, 8, 0, 0><<<2500, 512, 0, stream>>>(
        zs, 0, nbr3, Wbh, points, 10, 0, 0, 10, N3, N3, 2500);
}